// Round 13
// baseline (142.737 us; speedup 1.0000x reference)
//
#include <hip/hip_runtime.h>
#include <math.h>

#define NDIM 128
#define NHID 512
#define NEXPERT 64
#define NTOK 1024
#define NPAIR (NTOK * 2)

typedef __attribute__((ext_vector_type(8))) short short8_t;
typedef __attribute__((ext_vector_type(4))) float f32x4;

__device__ __forceinline__ float gelu_f(float v) {
    return 0.5f * v * (1.0f + erff(v * 0.7071067811865476f));
}
__device__ __forceinline__ unsigned short f2bf(float f) {
    union { float f; unsigned u; } v; v.f = f;
    unsigned r = v.u + 0x7FFFu + ((v.u >> 16) & 1u);
    return (unsigned short)(r >> 16);
}
__device__ __forceinline__ float bf2f(unsigned short h) {
    union { unsigned u; float f; } v; v.u = ((unsigned)h) << 16;
    return v.f;
}
__device__ __forceinline__ void split3(float f, short& ho, short& mo, short& lo) {
    const unsigned short h = f2bf(f);
    const float r1 = f - bf2f(h);
    const unsigned short m = f2bf(r1);
    const unsigned short l = f2bf(r1 - bf2f(m));
    ho = (short)h; mo = (short)m; lo = (short)l;
}

// ============ N1: gate1 (inline split of x,gw1) ∥ decomp(gw2) ============
__global__ __launch_bounds__(256) void k_g1d2(
        const float* __restrict__ x, const float* __restrict__ gw1,
        const float* __restrict__ gw2, const float* __restrict__ gb1,
        unsigned short* __restrict__ G2h, unsigned short* __restrict__ G2m,
        unsigned short* __restrict__ G2l, unsigned short* __restrict__ Hh,
        unsigned short* __restrict__ Hm, unsigned short* __restrict__ Hl) {
    __shared__ __align__(16) char smem[58112];
    const int j = threadIdx.x;
    if (blockIdx.x >= 256) {
        float (*T)[65] = (float (*)[65])smem;
        const int u = blockIdx.x - 256;
        const int k0 = (u >> 3) * 64, n0 = (u & 7) * 64;
#pragma unroll
        for (int q = 0; q < 4; ++q) {
            const int idx = j + 256 * q;
            const int kr = idx >> 4, c4 = idx & 15;
            float4 v = *(const float4*)(gw2 + (size_t)(k0 + kr) * NHID + n0 + c4 * 4);
            T[kr][c4 * 4 + 0] = v.x; T[kr][c4 * 4 + 1] = v.y;
            T[kr][c4 * 4 + 2] = v.z; T[kr][c4 * 4 + 3] = v.w;
        }
        __syncthreads();
#pragma unroll
        for (int q = 0; q < 4; ++q) {
            const int idx = j + 256 * q;
            const int n = idx >> 4, k4 = idx & 15;
            short4 sh, sm, sl;
#pragma unroll
            for (int qq = 0; qq < 4; ++qq)
                split3(T[k4 * 4 + qq][n], (&sh.x)[qq], (&sm.x)[qq], (&sl.x)[qq]);
            const size_t o = (size_t)(n0 + n) * NHID + k0 + k4 * 4;
            *(short4*)(G2h + o) = sh;
            *(short4*)(G2m + o) = sm;
            *(short4*)(G2l + o) = sl;
        }
        return;
    }
    short (*Ahs)[32][72] = (short (*)[32][72])smem;
    short (*Bss)[64][72] = (short (*)[64][72])(smem + 13824);
    float (*T)[65] = (float (*)[65])(smem + 41472);
    const int u = blockIdx.x;
    const int m0 = (u >> 3) * 32, n0 = (u & 7) * 64;
    const int w = j >> 6, lane = j & 63;
    const int mt = w & 1, npair = w >> 1;
    const int lrow = lane & 15, lseg = lane >> 4;
    f32x4 acc[2];
    acc[0] = (f32x4){0.f, 0.f, 0.f, 0.f};
    acc[1] = (f32x4){0.f, 0.f, 0.f, 0.f};
    for (int kc = 0; kc < NDIM; kc += 64) {
        __syncthreads();
#pragma unroll
        for (int q = 0; q < 4; ++q) {
            const int idx = j + 256 * q;
            const int kr = idx >> 4, c4 = idx & 15;
            float4 v = *(const float4*)(gw1 + (size_t)(kc + kr) * NHID + n0 + c4 * 4);
            T[kr][c4 * 4 + 0] = v.x; T[kr][c4 * 4 + 1] = v.y;
            T[kr][c4 * 4 + 2] = v.z; T[kr][c4 * 4 + 3] = v.w;
        }
#pragma unroll
        for (int q = 0; q < 2; ++q) {
            const int idx = j + 256 * q;
            const int row = idx >> 4, c4 = idx & 15;
            float4 v = *(const float4*)(x + (size_t)(m0 + row) * NDIM + kc + c4 * 4);
            short4 sh, sm, sl;
#pragma unroll
            for (int qq = 0; qq < 4; ++qq)
                split3((&v.x)[qq], (&sh.x)[qq], (&sm.x)[qq], (&sl.x)[qq]);
            *(short4*)&Ahs[0][row][c4 * 4] = sh;
            *(short4*)&Ahs[1][row][c4 * 4] = sm;
            *(short4*)&Ahs[2][row][c4 * 4] = sl;
        }
        __syncthreads();
#pragma unroll
        for (int q = 0; q < 4; ++q) {
            const int idx = j + 256 * q;
            const int nn = idx >> 4, k4 = idx & 15;
            short4 sh, sm, sl;
#pragma unroll
            for (int qq = 0; qq < 4; ++qq)
                split3(T[k4 * 4 + qq][nn], (&sh.x)[qq], (&sm.x)[qq], (&sl.x)[qq]);
            *(short4*)&Bss[0][nn][k4 * 4] = sh;
            *(short4*)&Bss[1][nn][k4 * 4] = sm;
            *(short4*)&Bss[2][nn][k4 * 4] = sl;
        }
        __syncthreads();
#pragma unroll
        for (int ks = 0; ks < 2; ++ks) {
            const int ko = ks * 32 + lseg * 8;
            short8_t ah = *(short8_t*)&Ahs[0][mt * 16 + lrow][ko];
            short8_t am = *(short8_t*)&Ahs[1][mt * 16 + lrow][ko];
            short8_t al = *(short8_t*)&Ahs[2][mt * 16 + lrow][ko];
#pragma unroll
            for (int nt = 0; nt < 2; ++nt) {
                const int nr = (npair * 2 + nt) * 16 + lrow;
                short8_t bh = *(short8_t*)&Bss[0][nr][ko];
                short8_t bm = *(short8_t*)&Bss[1][nr][ko];
                short8_t bl = *(short8_t*)&Bss[2][nr][ko];
                acc[nt] = __builtin_amdgcn_mfma_f32_16x16x32_bf16(ah, bh, acc[nt], 0, 0, 0);
                acc[nt] = __builtin_amdgcn_mfma_f32_16x16x32_bf16(am, bh, acc[nt], 0, 0, 0);
                acc[nt] = __builtin_amdgcn_mfma_f32_16x16x32_bf16(ah, bm, acc[nt], 0, 0, 0);
                acc[nt] = __builtin_amdgcn_mfma_f32_16x16x32_bf16(al, bh, acc[nt], 0, 0, 0);
                acc[nt] = __builtin_amdgcn_mfma_f32_16x16x32_bf16(ah, bl, acc[nt], 0, 0, 0);
                acc[nt] = __builtin_amdgcn_mfma_f32_16x16x32_bf16(am, bm, acc[nt], 0, 0, 0);
            }
        }
    }
#pragma unroll
    for (int nt = 0; nt < 2; ++nt) {
        const int col = n0 + (npair * 2 + nt) * 16 + lrow;
        const float bb = gb1[col];
#pragma unroll
        for (int r = 0; r < 4; ++r) {
            const int row = m0 + mt * 16 + lseg * 4 + r;
            const float h = gelu_f(acc[nt][r] + bb);
            short hh, hm, hl;
            split3(h, hh, hm, hl);
            const size_t o = (size_t)row * NHID + col;
            Hh[o] = (unsigned short)hh; Hm[o] = (unsigned short)hm;
            Hl[o] = (unsigned short)hl;
        }
    }
}

// ============ N2: gate2 = gelu(h1 @ gw2 + gb2) -> h2 f32 ============
__global__ __launch_bounds__(256) void k_gate2(
        const unsigned short* __restrict__ Ahp, const unsigned short* __restrict__ Amp,
        const unsigned short* __restrict__ Alp,
        const unsigned short* __restrict__ Bhp, const unsigned short* __restrict__ Bmp,
        const unsigned short* __restrict__ Blp,
        const float* __restrict__ gb2, float* __restrict__ h2) {
    __shared__ short Ahs[3][32][72];
    __shared__ short Bss[3][64][72];
    const int j = threadIdx.x;
    const int u = blockIdx.x;
    const int m0 = (u >> 3) * 32, n0 = (u & 7) * 64;
    const int w = j >> 6, lane = j & 63;
    const int mt = w & 1, npair = w >> 1;
    const int lrow = lane & 15, lseg = lane >> 4;
    const int K = NHID;
    f32x4 acc[2];
    acc[0] = (f32x4){0.f, 0.f, 0.f, 0.f};
    acc[1] = (f32x4){0.f, 0.f, 0.f, 0.f};
    for (int kc = 0; kc < K; kc += 64) {
        __syncthreads();
        {
            const int row = j >> 3, c8 = j & 7;
            const size_t o = (size_t)(m0 + row) * K + kc + c8 * 8;
            *(short8_t*)&Ahs[0][row][c8 * 8] = *(const short8_t*)(Ahp + o);
            *(short8_t*)&Ahs[1][row][c8 * 8] = *(const short8_t*)(Amp + o);
            *(short8_t*)&Ahs[2][row][c8 * 8] = *(const short8_t*)(Alp + o);
        }
#pragma unroll
        for (int q = 0; q < 2; ++q) {
            const int idx = j + 256 * q;
            const int nr = idx >> 3, c8 = idx & 7;
            const size_t o = (size_t)(n0 + nr) * K + kc + c8 * 8;
            *(short8_t*)&Bss[0][nr][c8 * 8] = *(const short8_t*)(Bhp + o);
            *(short8_t*)&Bss[1][nr][c8 * 8] = *(const short8_t*)(Bmp + o);
            *(short8_t*)&Bss[2][nr][c8 * 8] = *(const short8_t*)(Blp + o);
        }
        __syncthreads();
#pragma unroll
        for (int ks = 0; ks < 2; ++ks) {
            const int ko = ks * 32 + lseg * 8;
            short8_t ah = *(short8_t*)&Ahs[0][mt * 16 + lrow][ko];
            short8_t am = *(short8_t*)&Ahs[1][mt * 16 + lrow][ko];
            short8_t al = *(short8_t*)&Ahs[2][mt * 16 + lrow][ko];
#pragma unroll
            for (int nt = 0; nt < 2; ++nt) {
                const int nr = (npair * 2 + nt) * 16 + lrow;
                short8_t bh = *(short8_t*)&Bss[0][nr][ko];
                short8_t bm = *(short8_t*)&Bss[1][nr][ko];
                short8_t bl = *(short8_t*)&Bss[2][nr][ko];
                acc[nt] = __builtin_amdgcn_mfma_f32_16x16x32_bf16(ah, bh, acc[nt], 0, 0, 0);
                acc[nt] = __builtin_amdgcn_mfma_f32_16x16x32_bf16(am, bh, acc[nt], 0, 0, 0);
                acc[nt] = __builtin_amdgcn_mfma_f32_16x16x32_bf16(ah, bm, acc[nt], 0, 0, 0);
                acc[nt] = __builtin_amdgcn_mfma_f32_16x16x32_bf16(al, bh, acc[nt], 0, 0, 0);
                acc[nt] = __builtin_amdgcn_mfma_f32_16x16x32_bf16(ah, bl, acc[nt], 0, 0, 0);
                acc[nt] = __builtin_amdgcn_mfma_f32_16x16x32_bf16(am, bm, acc[nt], 0, 0, 0);
            }
        }
    }
#pragma unroll
    for (int nt = 0; nt < 2; ++nt) {
        const int col = n0 + (npair * 2 + nt) * 16 + lrow;
        const float bb = gb2[col];
#pragma unroll
        for (int r = 0; r < 4; ++r) {
            const int row = m0 + mt * 16 + lseg * 4 + r;
            h2[(size_t)row * NHID + col] = gelu_f(acc[nt][r] + bb);
        }
    }
}

// ============ N3: gate3 (256 blocks x 4 tokens) + out zero-init ============
__global__ __launch_bounds__(256) void k_gate3(
        const float* __restrict__ h2, const float* __restrict__ gw3,
        const float* __restrict__ gb3, int* __restrict__ eidx,
        float* __restrict__ wval, float* __restrict__ out) {
    __shared__ float hs[4][132];
    __shared__ float gs[128][72];
    const int j = threadIdx.x;
    const int lane = j & 63;
    const int w = j >> 6;
    const int t0 = blockIdx.x * 4;
    // zero out slice (out not re-poisoned between replays; we own init)
    ((float2*)out)[blockIdx.x * 256 + j] = make_float2(0.f, 0.f);
    float acc = 0.f;
    for (int k0 = 0; k0 < NHID; k0 += 128) {
        __syncthreads();
        if (j < 128) {
            const int tok = j >> 5, c4 = j & 31;
            *(float4*)&hs[tok][c4 * 4] =
                *(const float4*)(h2 + (size_t)(t0 + tok) * NHID + k0 + c4 * 4);
        }
#pragma unroll
        for (int q = 0; q < 8; ++q) {
            const int idx = j + 256 * q;
            const int kk = idx >> 4, c4 = idx & 15;
            *(float4*)&gs[kk][c4 * 4] =
                *(const float4*)(gw3 + (size_t)(k0 + kk) * NEXPERT + c4 * 4);
        }
        __syncthreads();
        for (int kk = 0; kk < 128; ++kk) acc += hs[w][kk] * gs[kk][lane];
    }
    const float bias = gb3[lane];
    {
        const int t = t0 + w;
        float s = 1.f / (1.f + expf(-(acc + bias)));
        float v = s; int ix = lane;
#pragma unroll
        for (int off = 32; off >= 1; off >>= 1) {
            float ov = __shfl_xor(v, off);
            int oi = __shfl_xor(ix, off);
            if (ov > v || (ov == v && oi < ix)) { v = ov; ix = oi; }
        }
        const float v0 = v; const int i0 = ix;
        float v2 = (lane == i0) ? -1.f : s; int ix2 = lane;
#pragma unroll
        for (int off = 32; off >= 1; off >>= 1) {
            float ov = __shfl_xor(v2, off);
            int oi = __shfl_xor(ix2, off);
            if (ov > v2 || (ov == v2 && oi < ix2)) { v2 = ov; ix2 = oi; }
        }
        if (lane == 0) {
            float inv = 1.f / (v0 + v2);
            eidx[t * 2] = i0;  eidx[t * 2 + 1] = ix2;
            wval[t * 2] = v0 * inv;  wval[t * 2 + 1] = v2 * inv;
        }
    }
}

// deterministic in-block list build (index-ascending; identical in all blocks
// of the same expert). Waves own disjoint 512-entry ranges; ballot-scan.
__device__ __forceinline__ int build_list(
        const int* __restrict__ eidx, int e, int lane, int w,
        int* lst, int* wtot) {
    unsigned long long msk[8];
    const int b0 = w * 512;
    int tot = 0;
#pragma unroll
    for (int c = 0; c < 8; ++c) {
        const int i = b0 + c * 64 + lane;
        msk[c] = __ballot(eidx[i] == e);
        tot += (int)__popcll(msk[c]);
    }
    if (lane == 0) wtot[w] = tot;
    __syncthreads();
    int woff = 0;
    for (int q = 0; q < w; ++q) woff += wtot[q];
    int run = 0;
#pragma unroll
    for (int c = 0; c < 8; ++c) {
        const int i = b0 + c * 64 + lane;
        if ((msk[c] >> lane) & 1ull)
            lst[woff + run + (int)__popcll(msk[c] & ((1ull << lane) - 1ull))] = i;
        run += (int)__popcll(msk[c]);
    }
    const int n = wtot[0] + wtot[1] + wtot[2] + wtot[3];
    __syncthreads();
    return n;
}

// ============ N4: expert FFN, fully in-block (l1 in LDS + full-K l2 + scatter)
// 128 blocks = (expert e) x (d-half). No inter-block sync: each block
// recomputes l1 for its expert (t kept in LDS), then l2 over full K=512,
// then atomicAdd of wval*gelu(...) into out (exactly 2 adds per out elem,
// onto zero -> bit-deterministic).
#define TROW 520  // shorts per t row (1040 B, 16B-aligned, odd*16 -> bank spread)
__global__ __launch_bounds__(256) void k_expert(
        const float* __restrict__ x, const float* __restrict__ W1,
        const float* __restrict__ B1, const float* __restrict__ W2,
        const float* __restrict__ B2, const int* __restrict__ eidx,
        const float* __restrict__ wval, float* __restrict__ out) {
    __shared__ short t_[32 * TROW];       // 33.3 KB
    __shared__ short As_[32 * 136];       // 8.7 KB
    __shared__ short Bs_[64 * 136];       // 17.4 KB
    __shared__ int prs[32];
    __shared__ int wtot[4];
    __shared__ int lst[NPAIR];            // 8 KB
    const int j = threadIdx.x;
    const int lane = j & 63;
    const int w = j >> 6;
    const int e = blockIdx.x >> 1;
    const int d0 = (blockIdx.x & 1) * 64;
    char* Asc = (char*)As_;
    char* Bsc = (char*)Bs_;
    char* tc = (char*)t_;
    const int n = build_list(eidx, e, lane, w, lst, wtot);
    const float* W1e = W1 + (size_t)e * NHID * NDIM;
    const float* W2e = W2 + (size_t)e * NDIM * NHID;
    const int lrow = lane & 15, lseg = lane >> 4;
    const int acol = lseg << 4;  // byte offset of k-segment
    const int brow = w * 16 + lrow;

    for (int bt = 0; bt * 32 < n; ++bt) {
        __syncthreads();
        if (j < 32) prs[j] = (bt * 32 + j < n) ? lst[bt * 32 + j] : -1;
        __syncthreads();
        // gather x rows -> As (bf16)
        for (int idx = j; idx < 1024; idx += 256) {
            const int tok = idx >> 5, c4 = idx & 31;
            const int pr = prs[tok];
            float4 v = make_float4(0.f, 0.f, 0.f, 0.f);
            if (pr >= 0) v = ((const float4*)x)[(size_t)(pr >> 1) * 32 + c4];
            short4 s; s.x = (short)f2bf(v.x); s.y = (short)f2bf(v.y);
            s.z = (short)f2bf(v.z); s.w = (short)f2bf(v.w);
            *(short4*)(Asc + tok * 272 + c4 * 8) = s;
        }
        // ---- l1: 8 f-chunks, t kept in LDS ----
        for (int fc = 0; fc < 8; ++fc) {
            const int f0 = fc * 64;
            __syncthreads();
            for (int idx = j; idx < 2048; idx += 256) {
                const int f = idx >> 5, c4 = idx & 31;
                float4 v = *(const float4*)(W1e + (size_t)(f0 + f) * NDIM + c4 * 4);
                short4 s; s.x = (short)f2bf(v.x); s.y = (short)f2bf(v.y);
                s.z = (short)f2bf(v.z); s.w = (short)f2bf(v.w);
                *(short4*)(Bsc + f * 272 + c4 * 8) = s;
            }
            __syncthreads();
            f32x4 acc[2];
            acc[0] = (f32x4){0.f, 0.f, 0.f, 0.f};
            acc[1] = (f32x4){0.f, 0.f, 0.f, 0.f};
#pragma unroll
            for (int ks = 0; ks < 4; ++ks) {
                short8_t b = *(short8_t*)(Bsc + brow * 272 + ks * 64 + acol);
#pragma unroll
                for (int mt = 0; mt < 2; ++mt) {
                    short8_t a = *(short8_t*)(Asc + (mt * 16 + lrow) * 272 + ks * 64 + acol);
                    acc[mt] = __builtin_amdgcn_mfma_f32_16x16x32_bf16(a, b, acc[mt], 0, 0, 0);
                }
            }
            const float bbias = B1[e * NHID + f0 + w * 16 + lrow];
            const int fcol = f0 + w * 16 + lrow;
#pragma unroll
            for (int mt = 0; mt < 2; ++mt) {
#pragma unroll
                for (int r = 0; r < 4; ++r) {
                    const int tok = mt * 16 + (lseg << 2) + r;
                    t_[tok * TROW + fcol] = (short)f2bf(gelu_f(acc[mt][r] + bbias));
                }
            }
        }
        // ---- l2: full K=512 from t_ in LDS, d-half d0 ----
        f32x4 acc2[2];
        acc2[0] = (f32x4){0.f, 0.f, 0.f, 0.f};
        acc2[1] = (f32x4){0.f, 0.f, 0.f, 0.f};
        for (int kc = 0; kc < 4; ++kc) {
            const int k0 = kc * 128;
            __syncthreads();
            for (int idx = j; idx < 2048; idx += 256) {
                const int d = idx >> 5, c4 = idx & 31;
                float4 v = *(const float4*)(W2e + (size_t)(d0 + d) * NHID + k0 + c4 * 4);
                short4 s; s.x = (short)f2bf(v.x); s.y = (short)f2bf(v.y);
                s.z = (short)f2bf(v.z); s.w = (short)f2bf(v.w);
                *(short4*)(Bsc + d * 272 + c4 * 8) = s;
            }
            __syncthreads();
#pragma unroll
            for (int ks = 0; ks < 4; ++ks) {
                short8_t b = *(short8_t*)(Bsc + brow * 272 + ks * 64 + acol);
#pragma unroll
                for (int mt = 0; mt < 2; ++mt) {
                    short8_t a = *(short8_t*)(tc + (mt * 16 + lrow) * (TROW * 2)
                                              + k0 * 2 + ks * 64 + acol);
                    acc2[mt] = __builtin_amdgcn_mfma_f32_16x16x32_bf16(a, b, acc2[mt], 0, 0, 0);
                }
            }
        }
        const float b2 = B2[e * NDIM + d0 + w * 16 + lrow];
        const int dcol = d0 + w * 16 + lrow;
#pragma unroll
        for (int mt = 0; mt < 2; ++mt) {
#pragma unroll
            for (int r = 0; r < 4; ++r) {
                const int tok = mt * 16 + (lseg << 2) + r;
                const int pr = prs[tok];
                if (pr >= 0) {
                    const float y = gelu_f(acc2[mt][r] + b2);
                    atomicAdd(&out[(size_t)(pr >> 1) * NDIM + dcol], wval[pr] * y);
                }
            }
        }
    }
}

extern "C" void kernel_launch(void* const* d_in, const int* in_sizes, int n_in,
                              void* d_out, int out_size, void* d_ws, size_t ws_size,
                              hipStream_t stream) {
    const float* x   = (const float*)d_in[0];
    const float* gw1 = (const float*)d_in[1];
    const float* gb1 = (const float*)d_in[2];
    const float* gw2 = (const float*)d_in[3];
    const float* gb2 = (const float*)d_in[4];
    const float* gw3 = (const float*)d_in[5];
    const float* gb3 = (const float*)d_in[6];
    const float* W1  = (const float*)d_in[7];
    const float* B1  = (const float*)d_in[8];
    const float* W2  = (const float*)d_in[9];
    const float* B2  = (const float*)d_in[10];
    float* out = (float*)d_out;
    char* ws = (char*)d_ws;

    // G2 planes [0,1.5M) | H planes [1.5M,4.5M) | h2 [4.5M,6.5M) | ctrl [7M..)
    unsigned short* G2h = (unsigned short*)(ws);
    unsigned short* G2m = (unsigned short*)(ws + 524288);
    unsigned short* G2l = (unsigned short*)(ws + 1048576);
    unsigned short* Hh  = (unsigned short*)(ws + 1572864);
    unsigned short* Hm  = (unsigned short*)(ws + 2621440);
    unsigned short* Hl  = (unsigned short*)(ws + 3670016);
    float*          h2  = (float*)(ws + 4718592);
    int*   eidx = (int*)  (ws + 7340032);
    float* wval = (float*)(ws + 7340032 + 8192);

    k_g1d2<<<dim3(320), 256, 0, stream>>>(x, gw1, gw2, gb1, G2h, G2m, G2l, Hh, Hm, Hl);
    k_gate2<<<dim3(256), 256, 0, stream>>>(Hh, Hm, Hl, G2h, G2m, G2l, gb2, h2);
    k_gate3<<<dim3(256), 256, 0, stream>>>(h2, gw3, gb3, eidx, wval, out);
    k_expert<<<dim3(128), 256, 0, stream>>>(x, W1, B1, W2, B2, eidx, wval, out);
}

// Round 14
// 66.232 us; speedup vs baseline: 2.1551x; 2.1551x over previous
//
#include <hip/hip_runtime.h>
#include <math.h>

#define NDIM 128
#define NHID 512
#define NEXPERT 64
#define NTOK 1024
#define NPAIR (NTOK * 2)

typedef __attribute__((ext_vector_type(8))) short short8_t;
typedef __attribute__((ext_vector_type(4))) float f32x4;

__device__ __forceinline__ float gelu_f(float v) {
    return 0.5f * v * (1.0f + erff(v * 0.7071067811865476f));
}
__device__ __forceinline__ unsigned short f2bf(float f) {
    union { float f; unsigned u; } v; v.f = f;
    unsigned r = v.u + 0x7FFFu + ((v.u >> 16) & 1u);
    return (unsigned short)(r >> 16);
}
__device__ __forceinline__ float bf2f(unsigned short h) {
    union { unsigned u; float f; } v; v.u = ((unsigned)h) << 16;
    return v.f;
}
__device__ __forceinline__ void split3(float f, short& ho, short& mo, short& lo) {
    const unsigned short h = f2bf(f);
    const float r1 = f - bf2f(h);
    const unsigned short m = f2bf(r1);
    const unsigned short l = f2bf(r1 - bf2f(m));
    ho = (short)h; mo = (short)m; lo = (short)l;
}

// ============ N1: gate1 (inline split of x,gw1) ∥ decomp(gw2) ============
__global__ __launch_bounds__(256) void k_g1d2(
        const float* __restrict__ x, const float* __restrict__ gw1,
        const float* __restrict__ gw2, const float* __restrict__ gb1,
        unsigned short* __restrict__ G2h, unsigned short* __restrict__ G2m,
        unsigned short* __restrict__ G2l, unsigned short* __restrict__ Hh,
        unsigned short* __restrict__ Hm, unsigned short* __restrict__ Hl) {
    __shared__ __align__(16) char smem[58112];
    const int j = threadIdx.x;
    if (blockIdx.x >= 256) {
        float (*T)[65] = (float (*)[65])smem;
        const int u = blockIdx.x - 256;
        const int k0 = (u >> 3) * 64, n0 = (u & 7) * 64;
#pragma unroll
        for (int q = 0; q < 4; ++q) {
            const int idx = j + 256 * q;
            const int kr = idx >> 4, c4 = idx & 15;
            float4 v = *(const float4*)(gw2 + (size_t)(k0 + kr) * NHID + n0 + c4 * 4);
            T[kr][c4 * 4 + 0] = v.x; T[kr][c4 * 4 + 1] = v.y;
            T[kr][c4 * 4 + 2] = v.z; T[kr][c4 * 4 + 3] = v.w;
        }
        __syncthreads();
#pragma unroll
        for (int q = 0; q < 4; ++q) {
            const int idx = j + 256 * q;
            const int n = idx >> 4, k4 = idx & 15;
            short4 sh, sm, sl;
#pragma unroll
            for (int qq = 0; qq < 4; ++qq)
                split3(T[k4 * 4 + qq][n], (&sh.x)[qq], (&sm.x)[qq], (&sl.x)[qq]);
            const size_t o = (size_t)(n0 + n) * NHID + k0 + k4 * 4;
            *(short4*)(G2h + o) = sh;
            *(short4*)(G2m + o) = sm;
            *(short4*)(G2l + o) = sl;
        }
        return;
    }
    short (*Ahs)[32][72] = (short (*)[32][72])smem;
    short (*Bss)[64][72] = (short (*)[64][72])(smem + 13824);
    float (*T)[65] = (float (*)[65])(smem + 41472);
    const int u = blockIdx.x;
    const int m0 = (u >> 3) * 32, n0 = (u & 7) * 64;
    const int w = j >> 6, lane = j & 63;
    const int mt = w & 1, npair = w >> 1;
    const int lrow = lane & 15, lseg = lane >> 4;
    f32x4 acc[2];
    acc[0] = (f32x4){0.f, 0.f, 0.f, 0.f};
    acc[1] = (f32x4){0.f, 0.f, 0.f, 0.f};
    for (int kc = 0; kc < NDIM; kc += 64) {
        __syncthreads();
#pragma unroll
        for (int q = 0; q < 4; ++q) {
            const int idx = j + 256 * q;
            const int kr = idx >> 4, c4 = idx & 15;
            float4 v = *(const float4*)(gw1 + (size_t)(kc + kr) * NHID + n0 + c4 * 4);
            T[kr][c4 * 4 + 0] = v.x; T[kr][c4 * 4 + 1] = v.y;
            T[kr][c4 * 4 + 2] = v.z; T[kr][c4 * 4 + 3] = v.w;
        }
#pragma unroll
        for (int q = 0; q < 2; ++q) {
            const int idx = j + 256 * q;
            const int row = idx >> 4, c4 = idx & 15;
            float4 v = *(const float4*)(x + (size_t)(m0 + row) * NDIM + kc + c4 * 4);
            short4 sh, sm, sl;
#pragma unroll
            for (int qq = 0; qq < 4; ++qq)
                split3((&v.x)[qq], (&sh.x)[qq], (&sm.x)[qq], (&sl.x)[qq]);
            *(short4*)&Ahs[0][row][c4 * 4] = sh;
            *(short4*)&Ahs[1][row][c4 * 4] = sm;
            *(short4*)&Ahs[2][row][c4 * 4] = sl;
        }
        __syncthreads();
#pragma unroll
        for (int q = 0; q < 4; ++q) {
            const int idx = j + 256 * q;
            const int nn = idx >> 4, k4 = idx & 15;
            short4 sh, sm, sl;
#pragma unroll
            for (int qq = 0; qq < 4; ++qq)
                split3(T[k4 * 4 + qq][nn], (&sh.x)[qq], (&sm.x)[qq], (&sl.x)[qq]);
            *(short4*)&Bss[0][nn][k4 * 4] = sh;
            *(short4*)&Bss[1][nn][k4 * 4] = sm;
            *(short4*)&Bss[2][nn][k4 * 4] = sl;
        }
        __syncthreads();
#pragma unroll
        for (int ks = 0; ks < 2; ++ks) {
            const int ko = ks * 32 + lseg * 8;
            short8_t ah = *(short8_t*)&Ahs[0][mt * 16 + lrow][ko];
            short8_t am = *(short8_t*)&Ahs[1][mt * 16 + lrow][ko];
            short8_t al = *(short8_t*)&Ahs[2][mt * 16 + lrow][ko];
#pragma unroll
            for (int nt = 0; nt < 2; ++nt) {
                const int nr = (npair * 2 + nt) * 16 + lrow;
                short8_t bh = *(short8_t*)&Bss[0][nr][ko];
                short8_t bm = *(short8_t*)&Bss[1][nr][ko];
                short8_t bl = *(short8_t*)&Bss[2][nr][ko];
                acc[nt] = __builtin_amdgcn_mfma_f32_16x16x32_bf16(ah, bh, acc[nt], 0, 0, 0);
                acc[nt] = __builtin_amdgcn_mfma_f32_16x16x32_bf16(am, bh, acc[nt], 0, 0, 0);
                acc[nt] = __builtin_amdgcn_mfma_f32_16x16x32_bf16(ah, bm, acc[nt], 0, 0, 0);
                acc[nt] = __builtin_amdgcn_mfma_f32_16x16x32_bf16(al, bh, acc[nt], 0, 0, 0);
                acc[nt] = __builtin_amdgcn_mfma_f32_16x16x32_bf16(ah, bl, acc[nt], 0, 0, 0);
                acc[nt] = __builtin_amdgcn_mfma_f32_16x16x32_bf16(am, bm, acc[nt], 0, 0, 0);
            }
        }
    }
#pragma unroll
    for (int nt = 0; nt < 2; ++nt) {
        const int col = n0 + (npair * 2 + nt) * 16 + lrow;
        const float bb = gb1[col];
#pragma unroll
        for (int r = 0; r < 4; ++r) {
            const int row = m0 + mt * 16 + lseg * 4 + r;
            const float h = gelu_f(acc[nt][r] + bb);
            short hh, hm, hl;
            split3(h, hh, hm, hl);
            const size_t o = (size_t)row * NHID + col;
            Hh[o] = (unsigned short)hh; Hm[o] = (unsigned short)hm;
            Hl[o] = (unsigned short)hl;
        }
    }
}

// ============ N2: gate2 = gelu(h1 @ gw2 + gb2) -> h2 f32 ============
__global__ __launch_bounds__(256) void k_gate2(
        const unsigned short* __restrict__ Ahp, const unsigned short* __restrict__ Amp,
        const unsigned short* __restrict__ Alp,
        const unsigned short* __restrict__ Bhp, const unsigned short* __restrict__ Bmp,
        const unsigned short* __restrict__ Blp,
        const float* __restrict__ gb2, float* __restrict__ h2) {
    __shared__ short Ahs[3][32][72];
    __shared__ short Bss[3][64][72];
    const int j = threadIdx.x;
    const int u = blockIdx.x;
    const int m0 = (u >> 3) * 32, n0 = (u & 7) * 64;
    const int w = j >> 6, lane = j & 63;
    const int mt = w & 1, npair = w >> 1;
    const int lrow = lane & 15, lseg = lane >> 4;
    const int K = NHID;
    f32x4 acc[2];
    acc[0] = (f32x4){0.f, 0.f, 0.f, 0.f};
    acc[1] = (f32x4){0.f, 0.f, 0.f, 0.f};
    for (int kc = 0; kc < K; kc += 64) {
        __syncthreads();
        {
            const int row = j >> 3, c8 = j & 7;
            const size_t o = (size_t)(m0 + row) * K + kc + c8 * 8;
            *(short8_t*)&Ahs[0][row][c8 * 8] = *(const short8_t*)(Ahp + o);
            *(short8_t*)&Ahs[1][row][c8 * 8] = *(const short8_t*)(Amp + o);
            *(short8_t*)&Ahs[2][row][c8 * 8] = *(const short8_t*)(Alp + o);
        }
#pragma unroll
        for (int q = 0; q < 2; ++q) {
            const int idx = j + 256 * q;
            const int nr = idx >> 3, c8 = idx & 7;
            const size_t o = (size_t)(n0 + nr) * K + kc + c8 * 8;
            *(short8_t*)&Bss[0][nr][c8 * 8] = *(const short8_t*)(Bhp + o);
            *(short8_t*)&Bss[1][nr][c8 * 8] = *(const short8_t*)(Bmp + o);
            *(short8_t*)&Bss[2][nr][c8 * 8] = *(const short8_t*)(Blp + o);
        }
        __syncthreads();
#pragma unroll
        for (int ks = 0; ks < 2; ++ks) {
            const int ko = ks * 32 + lseg * 8;
            short8_t ah = *(short8_t*)&Ahs[0][mt * 16 + lrow][ko];
            short8_t am = *(short8_t*)&Ahs[1][mt * 16 + lrow][ko];
            short8_t al = *(short8_t*)&Ahs[2][mt * 16 + lrow][ko];
#pragma unroll
            for (int nt = 0; nt < 2; ++nt) {
                const int nr = (npair * 2 + nt) * 16 + lrow;
                short8_t bh = *(short8_t*)&Bss[0][nr][ko];
                short8_t bm = *(short8_t*)&Bss[1][nr][ko];
                short8_t bl = *(short8_t*)&Bss[2][nr][ko];
                acc[nt] = __builtin_amdgcn_mfma_f32_16x16x32_bf16(ah, bh, acc[nt], 0, 0, 0);
                acc[nt] = __builtin_amdgcn_mfma_f32_16x16x32_bf16(am, bh, acc[nt], 0, 0, 0);
                acc[nt] = __builtin_amdgcn_mfma_f32_16x16x32_bf16(ah, bm, acc[nt], 0, 0, 0);
                acc[nt] = __builtin_amdgcn_mfma_f32_16x16x32_bf16(al, bh, acc[nt], 0, 0, 0);
                acc[nt] = __builtin_amdgcn_mfma_f32_16x16x32_bf16(ah, bl, acc[nt], 0, 0, 0);
                acc[nt] = __builtin_amdgcn_mfma_f32_16x16x32_bf16(am, bm, acc[nt], 0, 0, 0);
            }
        }
    }
#pragma unroll
    for (int nt = 0; nt < 2; ++nt) {
        const int col = n0 + (npair * 2 + nt) * 16 + lrow;
        const float bb = gb2[col];
#pragma unroll
        for (int r = 0; r < 4; ++r) {
            const int row = m0 + mt * 16 + lseg * 4 + r;
            h2[(size_t)row * NHID + col] = gelu_f(acc[nt][r] + bb);
        }
    }
}

// ============ N3: gate3 (256 blocks x 4 tokens) + out zero-init ============
__global__ __launch_bounds__(256) void k_gate3(
        const float* __restrict__ h2, const float* __restrict__ gw3,
        const float* __restrict__ gb3, int* __restrict__ eidx,
        float* __restrict__ wval, float* __restrict__ out) {
    __shared__ float hs[4][132];
    __shared__ float gs[128][72];
    const int j = threadIdx.x;
    const int lane = j & 63;
    const int w = j >> 6;
    const int t0 = blockIdx.x * 4;
    ((float2*)out)[blockIdx.x * 256 + j] = make_float2(0.f, 0.f);
    float acc = 0.f;
    for (int k0 = 0; k0 < NHID; k0 += 128) {
        __syncthreads();
        if (j < 128) {
            const int tok = j >> 5, c4 = j & 31;
            *(float4*)&hs[tok][c4 * 4] =
                *(const float4*)(h2 + (size_t)(t0 + tok) * NHID + k0 + c4 * 4);
        }
#pragma unroll
        for (int q = 0; q < 8; ++q) {
            const int idx = j + 256 * q;
            const int kk = idx >> 4, c4 = idx & 15;
            *(float4*)&gs[kk][c4 * 4] =
                *(const float4*)(gw3 + (size_t)(k0 + kk) * NEXPERT + c4 * 4);
        }
        __syncthreads();
        for (int kk = 0; kk < 128; ++kk) acc += hs[w][kk] * gs[kk][lane];
    }
    const float bias = gb3[lane];
    {
        const int t = t0 + w;
        float s = 1.f / (1.f + expf(-(acc + bias)));
        float v = s; int ix = lane;
#pragma unroll
        for (int off = 32; off >= 1; off >>= 1) {
            float ov = __shfl_xor(v, off);
            int oi = __shfl_xor(ix, off);
            if (ov > v || (ov == v && oi < ix)) { v = ov; ix = oi; }
        }
        const float v0 = v; const int i0 = ix;
        float v2 = (lane == i0) ? -1.f : s; int ix2 = lane;
#pragma unroll
        for (int off = 32; off >= 1; off >>= 1) {
            float ov = __shfl_xor(v2, off);
            int oi = __shfl_xor(ix2, off);
            if (ov > v2 || (ov == v2 && oi < ix2)) { v2 = ov; ix2 = oi; }
        }
        if (lane == 0) {
            float inv = 1.f / (v0 + v2);
            eidx[t * 2] = i0;  eidx[t * 2 + 1] = ix2;
            wval[t * 2] = v0 * inv;  wval[t * 2 + 1] = v2 * inv;
        }
    }
}

// deterministic in-block list build (index-ascending; identical in all blocks
// of the same expert). Waves own disjoint 512-entry ranges; ballot-scan.
__device__ __forceinline__ int build_list(
        const int* __restrict__ eidx, int e, int lane, int w,
        int* lst, int* wtot) {
    unsigned long long msk[8];
    const int b0 = w * 512;
    int tot = 0;
#pragma unroll
    for (int c = 0; c < 8; ++c) {
        const int i = b0 + c * 64 + lane;
        msk[c] = __ballot(eidx[i] == e);
        tot += (int)__popcll(msk[c]);
    }
    if (lane == 0) wtot[w] = tot;
    __syncthreads();
    int woff = 0;
    for (int q = 0; q < w; ++q) woff += wtot[q];
    int run = 0;
#pragma unroll
    for (int c = 0; c < 8; ++c) {
        const int i = b0 + c * 64 + lane;
        if ((msk[c] >> lane) & 1ull)
            lst[woff + run + (int)__popcll(msk[c] & ((1ull << lane) - 1ull))] = i;
        run += (int)__popcll(msk[c]);
    }
    const int n = wtot[0] + wtot[1] + wtot[2] + wtot[3];
    __syncthreads();
    return n;
}

// ============ N4: expert layer1 (bf16 MFMA, 512 blocks) -> tbuf ============
__global__ __launch_bounds__(256) void k_l1(
        const float* __restrict__ x, const float* __restrict__ W1,
        const float* __restrict__ B1, const int* __restrict__ eidx,
        unsigned short* __restrict__ tbuf) {
    __shared__ short As_[32 * 136];
    __shared__ short Bs_[64 * 136];
    __shared__ int prs[32];
    __shared__ int wtot[4];
    __shared__ int lst[NPAIR];
    const int j = threadIdx.x;
    const int lane = j & 63;
    const int w = j >> 6;
    const int e = blockIdx.x >> 3;
    const int f0 = (blockIdx.x & 7) * 64;
    char* Asc = (char*)As_;
    char* Bsc = (char*)Bs_;
    const int n = build_list(eidx, e, lane, w, lst, wtot);
    const float* W1e = W1 + (size_t)e * NHID * NDIM;
    for (int idx = j; idx < 2048; idx += 256) {
        const int f = idx >> 5, c4 = idx & 31;
        float4 v = *(const float4*)(W1e + (size_t)(f0 + f) * NDIM + c4 * 4);
        short4 s; s.x = (short)f2bf(v.x); s.y = (short)f2bf(v.y);
        s.z = (short)f2bf(v.z); s.w = (short)f2bf(v.w);
        *(short4*)(Bsc + f * 272 + c4 * 8) = s;
    }
    const float bbias = B1[e * NHID + f0 + w * 16 + (lane & 15)];
    for (int bt = 0; bt * 32 < n; ++bt) {
        __syncthreads();
        if (j < 32) prs[j] = (bt * 32 + j < n) ? lst[bt * 32 + j] : -1;
        __syncthreads();
        for (int idx = j; idx < 1024; idx += 256) {
            const int tok = idx >> 5, c4 = idx & 31;
            const int pr = prs[tok];
            float4 v = make_float4(0.f, 0.f, 0.f, 0.f);
            if (pr >= 0) v = ((const float4*)x)[(size_t)(pr >> 1) * 32 + c4];
            short4 s; s.x = (short)f2bf(v.x); s.y = (short)f2bf(v.y);
            s.z = (short)f2bf(v.z); s.w = (short)f2bf(v.w);
            *(short4*)(Asc + tok * 272 + c4 * 8) = s;
        }
        __syncthreads();
        f32x4 acc[2];
        acc[0] = (f32x4){0.f, 0.f, 0.f, 0.f};
        acc[1] = (f32x4){0.f, 0.f, 0.f, 0.f};
        const int acol = ((lane >> 4) << 4);
        const int brow = w * 16 + (lane & 15);
#pragma unroll
        for (int ks = 0; ks < 4; ++ks) {
            short8_t b = *(short8_t*)(Bsc + brow * 272 + ks * 64 + acol);
#pragma unroll
            for (int mt = 0; mt < 2; ++mt) {
                short8_t a = *(short8_t*)(Asc + (mt * 16 + (lane & 15)) * 272 + ks * 64 + acol);
                acc[mt] = __builtin_amdgcn_mfma_f32_16x16x32_bf16(a, b, acc[mt], 0, 0, 0);
            }
        }
        const int fcol = f0 + w * 16 + (lane & 15);
#pragma unroll
        for (int mt = 0; mt < 2; ++mt) {
#pragma unroll
            for (int r = 0; r < 4; ++r) {
                const int tok = mt * 16 + ((lane >> 4) << 2) + r;
                const int pr = prs[tok];
                if (pr >= 0)
                    tbuf[(size_t)pr * NHID + fcol] = f2bf(gelu_f(acc[mt][r] + bbias));
            }
        }
    }
}

// ============ N5: expert layer2 full-K + fused combine (atomicAdd) ============
// 512 blocks = (e, d-half, batch-stride 4). Full K=512 sequential; out gets
// exactly 2 commutative f32 adds per element onto gate3's zero -> deterministic.
#define TROW 520  // shorts per t row (1040 B)
__global__ __launch_bounds__(256) void k_l2(
        const float* __restrict__ W2, const float* __restrict__ B2,
        const int* __restrict__ eidx, const float* __restrict__ wval,
        const unsigned short* __restrict__ tbuf, float* __restrict__ out) {
    __shared__ short t_[32 * TROW];   // 33.3 KB
    __shared__ short Bs_[64 * 136];   // 17.4 KB
    __shared__ int prs[32];
    __shared__ int wtot[4];
    __shared__ int lst[NPAIR];        // 8 KB
    const int j = threadIdx.x;
    const int lane = j & 63;
    const int w = j >> 6;
    const int e = blockIdx.x >> 3;
    const int u = blockIdx.x & 7;
    const int d0 = (u & 1) * 64;
    const int mb = u >> 1;            // batch stride 4
    char* Bsc = (char*)Bs_;
    char* tc = (char*)t_;
    const int n = build_list(eidx, e, lane, w, lst, wtot);
    const float* W2e = W2 + (size_t)e * NDIM * NHID;
    const int lrow = lane & 15, lseg = lane >> 4;
    const int acol = lseg << 4;
    const int brow = w * 16 + lrow;
    const float b2 = B2[e * NDIM + d0 + w * 16 + lrow];
    const int dcol = d0 + w * 16 + lrow;
    for (int bt = mb; bt * 32 < n; bt += 4) {
        __syncthreads();
        if (j < 32) prs[j] = (bt * 32 + j < n) ? lst[bt * 32 + j] : -1;
        __syncthreads();
        // stage t rows, full K: 32 tok x 64 short8
        for (int idx = j; idx < 2048; idx += 256) {
            const int tok = idx >> 6, c8 = idx & 63;
            const int pr = prs[tok];
            short8_t v = (short8_t)(short)0;
            if (pr >= 0) v = *(const short8_t*)(tbuf + (size_t)pr * NHID + c8 * 8);
            *(short8_t*)(tc + tok * (TROW * 2) + c8 * 16) = v;
        }
        f32x4 acc2[2];
        acc2[0] = (f32x4){0.f, 0.f, 0.f, 0.f};
        acc2[1] = (f32x4){0.f, 0.f, 0.f, 0.f};
        for (int kc = 0; kc < 4; ++kc) {
            const int k0 = kc * 128;
            __syncthreads();
            for (int idx = j; idx < 2048; idx += 256) {
                const int d = idx >> 5, c4 = idx & 31;
                float4 v = *(const float4*)(W2e + (size_t)(d0 + d) * NHID + k0 + c4 * 4);
                short4 s; s.x = (short)f2bf(v.x); s.y = (short)f2bf(v.y);
                s.z = (short)f2bf(v.z); s.w = (short)f2bf(v.w);
                *(short4*)(Bsc + d * 272 + c4 * 8) = s;
            }
            __syncthreads();
#pragma unroll
            for (int ks = 0; ks < 4; ++ks) {
                short8_t b = *(short8_t*)(Bsc + brow * 272 + ks * 64 + acol);
#pragma unroll
                for (int mt = 0; mt < 2; ++mt) {
                    short8_t a = *(short8_t*)(tc + (mt * 16 + lrow) * (TROW * 2)
                                              + k0 * 2 + ks * 64 + acol);
                    acc2[mt] = __builtin_amdgcn_mfma_f32_16x16x32_bf16(a, b, acc2[mt], 0, 0, 0);
                }
            }
        }
#pragma unroll
        for (int mt = 0; mt < 2; ++mt) {
#pragma unroll
            for (int r = 0; r < 4; ++r) {
                const int tok = mt * 16 + (lseg << 2) + r;
                const int pr = prs[tok];
                if (pr >= 0) {
                    const float y = gelu_f(acc2[mt][r] + b2);
                    atomicAdd(&out[(size_t)(pr >> 1) * NDIM + dcol], wval[pr] * y);
                }
            }
        }
    }
}

extern "C" void kernel_launch(void* const* d_in, const int* in_sizes, int n_in,
                              void* d_out, int out_size, void* d_ws, size_t ws_size,
                              hipStream_t stream) {
    const float* x   = (const float*)d_in[0];
    const float* gw1 = (const float*)d_in[1];
    const float* gb1 = (const float*)d_in[2];
    const float* gw2 = (const float*)d_in[3];
    const float* gb2 = (const float*)d_in[4];
    const float* gw3 = (const float*)d_in[5];
    const float* gb3 = (const float*)d_in[6];
    const float* W1  = (const float*)d_in[7];
    const float* B1  = (const float*)d_in[8];
    const float* W2  = (const float*)d_in[9];
    const float* B2  = (const float*)d_in[10];
    float* out = (float*)d_out;
    char* ws = (char*)d_ws;

    // G2 planes [0,1.5M) | H planes [1.5M,4.5M) | h2 [4.5M,6.5M) |
    // tbuf [0,2M) (aliases G2+Hh-head, dead after gate2) | ctrl [7M..)
    unsigned short* G2h = (unsigned short*)(ws);
    unsigned short* G2m = (unsigned short*)(ws + 524288);
    unsigned short* G2l = (unsigned short*)(ws + 1048576);
    unsigned short* Hh  = (unsigned short*)(ws + 1572864);
    unsigned short* Hm  = (unsigned short*)(ws + 2621440);
    unsigned short* Hl  = (unsigned short*)(ws + 3670016);
    float*          h2  = (float*)(ws + 4718592);
    unsigned short* tbuf = (unsigned short*)(ws);
    int*   eidx = (int*)  (ws + 7340032);
    float* wval = (float*)(ws + 7340032 + 8192);

    k_g1d2<<<dim3(320), 256, 0, stream>>>(x, gw1, gw2, gb1, G2h, G2m, G2l, Hh, Hm, Hl);
    k_gate2<<<dim3(256), 256, 0, stream>>>(Hh, Hm, Hl, G2h, G2m, G2l, gb2, h2);
    k_gate3<<<dim3(256), 256, 0, stream>>>(h2, gw3, gb3, eidx, wval, out);
    k_l1<<<dim3(512), 256, 0, stream>>>(x, W1, B1, eidx, tbuf);
    k_l2<<<dim3(512), 256, 0, stream>>>(W2, B2, eidx, wval, tbuf, out);
}

// Round 15
// 59.134 us; speedup vs baseline: 2.4138x; 1.1200x over previous
//
#include <hip/hip_runtime.h>
#include <math.h>

#define NDIM 128
#define NHID 512
#define NEXPERT 64
#define NTOK 1024
#define NPAIR (NTOK * 2)

typedef __attribute__((ext_vector_type(8))) short short8_t;
typedef __attribute__((ext_vector_type(4))) float f32x4;

__device__ __forceinline__ float gelu_f(float v) {
    return 0.5f * v * (1.0f + erff(v * 0.7071067811865476f));
}
__device__ __forceinline__ unsigned short f2bf(float f) {
    union { float f; unsigned u; } v; v.f = f;
    unsigned r = v.u + 0x7FFFu + ((v.u >> 16) & 1u);
    return (unsigned short)(r >> 16);
}
__device__ __forceinline__ float bf2f(unsigned short h) {
    union { unsigned u; float f; } v; v.u = ((unsigned)h) << 16;
    return v.f;
}
__device__ __forceinline__ void split3(float f, short& ho, short& mo, short& lo) {
    const unsigned short h = f2bf(f);
    const float r1 = f - bf2f(h);
    const unsigned short m = f2bf(r1);
    const unsigned short l = f2bf(r1 - bf2f(m));
    ho = (short)h; mo = (short)m; lo = (short)l;
}

// ============ N1: gate1 (inline split of x,gw1) ∥ decomp(gw2) ============
__global__ __launch_bounds__(256) void k_g1d2(
        const float* __restrict__ x, const float* __restrict__ gw1,
        const float* __restrict__ gw2, const float* __restrict__ gb1,
        unsigned short* __restrict__ G2h, unsigned short* __restrict__ G2m,
        unsigned short* __restrict__ G2l, unsigned short* __restrict__ Hh,
        unsigned short* __restrict__ Hm, unsigned short* __restrict__ Hl) {
    __shared__ __align__(16) char smem[58112];
    const int j = threadIdx.x;
    if (blockIdx.x >= 256) {
        float (*T)[65] = (float (*)[65])smem;
        const int u = blockIdx.x - 256;
        const int k0 = (u >> 3) * 64, n0 = (u & 7) * 64;
#pragma unroll
        for (int q = 0; q < 4; ++q) {
            const int idx = j + 256 * q;
            const int kr = idx >> 4, c4 = idx & 15;
            float4 v = *(const float4*)(gw2 + (size_t)(k0 + kr) * NHID + n0 + c4 * 4);
            T[kr][c4 * 4 + 0] = v.x; T[kr][c4 * 4 + 1] = v.y;
            T[kr][c4 * 4 + 2] = v.z; T[kr][c4 * 4 + 3] = v.w;
        }
        __syncthreads();
#pragma unroll
        for (int q = 0; q < 4; ++q) {
            const int idx = j + 256 * q;
            const int n = idx >> 4, k4 = idx & 15;
            short4 sh, sm, sl;
#pragma unroll
            for (int qq = 0; qq < 4; ++qq)
                split3(T[k4 * 4 + qq][n], (&sh.x)[qq], (&sm.x)[qq], (&sl.x)[qq]);
            const size_t o = (size_t)(n0 + n) * NHID + k0 + k4 * 4;
            *(short4*)(G2h + o) = sh;
            *(short4*)(G2m + o) = sm;
            *(short4*)(G2l + o) = sl;
        }
        return;
    }
    short (*Ahs)[32][72] = (short (*)[32][72])smem;
    short (*Bss)[64][72] = (short (*)[64][72])(smem + 13824);
    float (*T)[65] = (float (*)[65])(smem + 41472);
    const int u = blockIdx.x;
    const int m0 = (u >> 3) * 32, n0 = (u & 7) * 64;
    const int w = j >> 6, lane = j & 63;
    const int mt = w & 1, npair = w >> 1;
    const int lrow = lane & 15, lseg = lane >> 4;
    f32x4 acc[2];
    acc[0] = (f32x4){0.f, 0.f, 0.f, 0.f};
    acc[1] = (f32x4){0.f, 0.f, 0.f, 0.f};
    for (int kc = 0; kc < NDIM; kc += 64) {
        __syncthreads();
#pragma unroll
        for (int q = 0; q < 4; ++q) {
            const int idx = j + 256 * q;
            const int kr = idx >> 4, c4 = idx & 15;
            float4 v = *(const float4*)(gw1 + (size_t)(kc + kr) * NHID + n0 + c4 * 4);
            T[kr][c4 * 4 + 0] = v.x; T[kr][c4 * 4 + 1] = v.y;
            T[kr][c4 * 4 + 2] = v.z; T[kr][c4 * 4 + 3] = v.w;
        }
#pragma unroll
        for (int q = 0; q < 2; ++q) {
            const int idx = j + 256 * q;
            const int row = idx >> 4, c4 = idx & 15;
            float4 v = *(const float4*)(x + (size_t)(m0 + row) * NDIM + kc + c4 * 4);
            short4 sh, sm, sl;
#pragma unroll
            for (int qq = 0; qq < 4; ++qq)
                split3((&v.x)[qq], (&sh.x)[qq], (&sm.x)[qq], (&sl.x)[qq]);
            *(short4*)&Ahs[0][row][c4 * 4] = sh;
            *(short4*)&Ahs[1][row][c4 * 4] = sm;
            *(short4*)&Ahs[2][row][c4 * 4] = sl;
        }
        __syncthreads();
#pragma unroll
        for (int q = 0; q < 4; ++q) {
            const int idx = j + 256 * q;
            const int nn = idx >> 4, k4 = idx & 15;
            short4 sh, sm, sl;
#pragma unroll
            for (int qq = 0; qq < 4; ++qq)
                split3(T[k4 * 4 + qq][nn], (&sh.x)[qq], (&sm.x)[qq], (&sl.x)[qq]);
            *(short4*)&Bss[0][nn][k4 * 4] = sh;
            *(short4*)&Bss[1][nn][k4 * 4] = sm;
            *(short4*)&Bss[2][nn][k4 * 4] = sl;
        }
        __syncthreads();
#pragma unroll
        for (int ks = 0; ks < 2; ++ks) {
            const int ko = ks * 32 + lseg * 8;
            short8_t ah = *(short8_t*)&Ahs[0][mt * 16 + lrow][ko];
            short8_t am = *(short8_t*)&Ahs[1][mt * 16 + lrow][ko];
            short8_t al = *(short8_t*)&Ahs[2][mt * 16 + lrow][ko];
#pragma unroll
            for (int nt = 0; nt < 2; ++nt) {
                const int nr = (npair * 2 + nt) * 16 + lrow;
                short8_t bh = *(short8_t*)&Bss[0][nr][ko];
                short8_t bm = *(short8_t*)&Bss[1][nr][ko];
                short8_t bl = *(short8_t*)&Bss[2][nr][ko];
                acc[nt] = __builtin_amdgcn_mfma_f32_16x16x32_bf16(ah, bh, acc[nt], 0, 0, 0);
                acc[nt] = __builtin_amdgcn_mfma_f32_16x16x32_bf16(am, bh, acc[nt], 0, 0, 0);
                acc[nt] = __builtin_amdgcn_mfma_f32_16x16x32_bf16(ah, bm, acc[nt], 0, 0, 0);
                acc[nt] = __builtin_amdgcn_mfma_f32_16x16x32_bf16(al, bh, acc[nt], 0, 0, 0);
                acc[nt] = __builtin_amdgcn_mfma_f32_16x16x32_bf16(ah, bl, acc[nt], 0, 0, 0);
                acc[nt] = __builtin_amdgcn_mfma_f32_16x16x32_bf16(am, bm, acc[nt], 0, 0, 0);
            }
        }
    }
#pragma unroll
    for (int nt = 0; nt < 2; ++nt) {
        const int col = n0 + (npair * 2 + nt) * 16 + lrow;
        const float bb = gb1[col];
#pragma unroll
        for (int r = 0; r < 4; ++r) {
            const int row = m0 + mt * 16 + lseg * 4 + r;
            const float h = gelu_f(acc[nt][r] + bb);
            short hh, hm, hl;
            split3(h, hh, hm, hl);
            const size_t o = (size_t)row * NHID + col;
            Hh[o] = (unsigned short)hh; Hm[o] = (unsigned short)hm;
            Hl[o] = (unsigned short)hl;
        }
    }
}

// ============ N2: gate2 = gelu(h1 @ gw2 + gb2) -> h2 f32 ============
__global__ __launch_bounds__(256) void k_gate2(
        const unsigned short* __restrict__ Ahp, const unsigned short* __restrict__ Amp,
        const unsigned short* __restrict__ Alp,
        const unsigned short* __restrict__ Bhp, const unsigned short* __restrict__ Bmp,
        const unsigned short* __restrict__ Blp,
        const float* __restrict__ gb2, float* __restrict__ h2) {
    __shared__ short Ahs[3][32][72];
    __shared__ short Bss[3][64][72];
    const int j = threadIdx.x;
    const int u = blockIdx.x;
    const int m0 = (u >> 3) * 32, n0 = (u & 7) * 64;
    const int w = j >> 6, lane = j & 63;
    const int mt = w & 1, npair = w >> 1;
    const int lrow = lane & 15, lseg = lane >> 4;
    const int K = NHID;
    f32x4 acc[2];
    acc[0] = (f32x4){0.f, 0.f, 0.f, 0.f};
    acc[1] = (f32x4){0.f, 0.f, 0.f, 0.f};
    for (int kc = 0; kc < K; kc += 64) {
        __syncthreads();
        {
            const int row = j >> 3, c8 = j & 7;
            const size_t o = (size_t)(m0 + row) * K + kc + c8 * 8;
            *(short8_t*)&Ahs[0][row][c8 * 8] = *(const short8_t*)(Ahp + o);
            *(short8_t*)&Ahs[1][row][c8 * 8] = *(const short8_t*)(Amp + o);
            *(short8_t*)&Ahs[2][row][c8 * 8] = *(const short8_t*)(Alp + o);
        }
#pragma unroll
        for (int q = 0; q < 2; ++q) {
            const int idx = j + 256 * q;
            const int nr = idx >> 3, c8 = idx & 7;
            const size_t o = (size_t)(n0 + nr) * K + kc + c8 * 8;
            *(short8_t*)&Bss[0][nr][c8 * 8] = *(const short8_t*)(Bhp + o);
            *(short8_t*)&Bss[1][nr][c8 * 8] = *(const short8_t*)(Bmp + o);
            *(short8_t*)&Bss[2][nr][c8 * 8] = *(const short8_t*)(Blp + o);
        }
        __syncthreads();
#pragma unroll
        for (int ks = 0; ks < 2; ++ks) {
            const int ko = ks * 32 + lseg * 8;
            short8_t ah = *(short8_t*)&Ahs[0][mt * 16 + lrow][ko];
            short8_t am = *(short8_t*)&Ahs[1][mt * 16 + lrow][ko];
            short8_t al = *(short8_t*)&Ahs[2][mt * 16 + lrow][ko];
#pragma unroll
            for (int nt = 0; nt < 2; ++nt) {
                const int nr = (npair * 2 + nt) * 16 + lrow;
                short8_t bh = *(short8_t*)&Bss[0][nr][ko];
                short8_t bm = *(short8_t*)&Bss[1][nr][ko];
                short8_t bl = *(short8_t*)&Bss[2][nr][ko];
                acc[nt] = __builtin_amdgcn_mfma_f32_16x16x32_bf16(ah, bh, acc[nt], 0, 0, 0);
                acc[nt] = __builtin_amdgcn_mfma_f32_16x16x32_bf16(am, bh, acc[nt], 0, 0, 0);
                acc[nt] = __builtin_amdgcn_mfma_f32_16x16x32_bf16(ah, bm, acc[nt], 0, 0, 0);
                acc[nt] = __builtin_amdgcn_mfma_f32_16x16x32_bf16(al, bh, acc[nt], 0, 0, 0);
                acc[nt] = __builtin_amdgcn_mfma_f32_16x16x32_bf16(ah, bl, acc[nt], 0, 0, 0);
                acc[nt] = __builtin_amdgcn_mfma_f32_16x16x32_bf16(am, bm, acc[nt], 0, 0, 0);
            }
        }
    }
#pragma unroll
    for (int nt = 0; nt < 2; ++nt) {
        const int col = n0 + (npair * 2 + nt) * 16 + lrow;
        const float bb = gb2[col];
#pragma unroll
        for (int r = 0; r < 4; ++r) {
            const int row = m0 + mt * 16 + lseg * 4 + r;
            h2[(size_t)row * NHID + col] = gelu_f(acc[nt][r] + bb);
        }
    }
}

// ============ N3: gate3 (256 blocks x 4 tokens, 1 token/wave) ============
__global__ __launch_bounds__(256) void k_gate3(
        const float* __restrict__ h2, const float* __restrict__ gw3,
        const float* __restrict__ gb3, int* __restrict__ eidx,
        float* __restrict__ wval) {
    __shared__ float hs[4][132];
    __shared__ float gs[128][72];
    const int j = threadIdx.x;
    const int lane = j & 63;
    const int w = j >> 6;
    const int t0 = blockIdx.x * 4;
    float acc = 0.f;
    for (int k0 = 0; k0 < NHID; k0 += 128) {
        __syncthreads();
        if (j < 128) {
            const int tok = j >> 5, c4 = j & 31;
            *(float4*)&hs[tok][c4 * 4] =
                *(const float4*)(h2 + (size_t)(t0 + tok) * NHID + k0 + c4 * 4);
        }
#pragma unroll
        for (int q = 0; q < 8; ++q) {
            const int idx = j + 256 * q;
            const int kk = idx >> 4, c4 = idx & 15;
            *(float4*)&gs[kk][c4 * 4] =
                *(const float4*)(gw3 + (size_t)(k0 + kk) * NEXPERT + c4 * 4);
        }
        __syncthreads();
        for (int kk = 0; kk < 128; ++kk) acc += hs[w][kk] * gs[kk][lane];
    }
    const float bias = gb3[lane];
    {
        const int t = t0 + w;
        float s = 1.f / (1.f + expf(-(acc + bias)));
        float v = s; int ix = lane;
#pragma unroll
        for (int off = 32; off >= 1; off >>= 1) {
            float ov = __shfl_xor(v, off);
            int oi = __shfl_xor(ix, off);
            if (ov > v || (ov == v && oi < ix)) { v = ov; ix = oi; }
        }
        const float v0 = v; const int i0 = ix;
        float v2 = (lane == i0) ? -1.f : s; int ix2 = lane;
#pragma unroll
        for (int off = 32; off >= 1; off >>= 1) {
            float ov = __shfl_xor(v2, off);
            int oi = __shfl_xor(ix2, off);
            if (ov > v2 || (ov == v2 && oi < ix2)) { v2 = ov; ix2 = oi; }
        }
        if (lane == 0) {
            float inv = 1.f / (v0 + v2);
            eidx[t * 2] = i0;  eidx[t * 2 + 1] = ix2;
            wval[t * 2] = v0 * inv;  wval[t * 2 + 1] = v2 * inv;
        }
    }
}

// deterministic in-block list build (index-ascending; identical in all blocks
// of the same expert). Waves own disjoint 512-entry ranges; ballot-scan.
__device__ __forceinline__ int build_list(
        const int* __restrict__ eidx, int e, int lane, int w,
        int* lst, int* wtot) {
    unsigned long long msk[8];
    const int b0 = w * 512;
    int tot = 0;
#pragma unroll
    for (int c = 0; c < 8; ++c) {
        const int i = b0 + c * 64 + lane;
        msk[c] = __ballot(eidx[i] == e);
        tot += (int)__popcll(msk[c]);
    }
    if (lane == 0) wtot[w] = tot;
    __syncthreads();
    int woff = 0;
    for (int q = 0; q < w; ++q) woff += wtot[q];
    int run = 0;
#pragma unroll
    for (int c = 0; c < 8; ++c) {
        const int i = b0 + c * 64 + lane;
        if ((msk[c] >> lane) & 1ull)
            lst[woff + run + (int)__popcll(msk[c] & ((1ull << lane) - 1ull))] = i;
        run += (int)__popcll(msk[c]);
    }
    const int n = wtot[0] + wtot[1] + wtot[2] + wtot[3];
    __syncthreads();
    return n;
}

// ============ N4: expert layer1 (bf16 MFMA, 512 blocks, XCD-local e) ============
// e = blockIdx&63: all 8 f-chunk blocks of expert e land on XCD e%8 (64%8==0),
// so W1[e] and the x-gathers stay in one L2.
__global__ __launch_bounds__(256) void k_l1(
        const float* __restrict__ x, const float* __restrict__ W1,
        const float* __restrict__ B1, const int* __restrict__ eidx,
        unsigned short* __restrict__ tbuf) {
    __shared__ short As_[32 * 136];
    __shared__ short Bs_[64 * 136];
    __shared__ int prs[32];
    __shared__ int wtot[4];
    __shared__ int lst[NPAIR];
    const int j = threadIdx.x;
    const int lane = j & 63;
    const int w = j >> 6;
    const int e = blockIdx.x & 63;
    const int f0 = (blockIdx.x >> 6) * 64;
    char* Asc = (char*)As_;
    char* Bsc = (char*)Bs_;
    const int n = build_list(eidx, e, lane, w, lst, wtot);
    const float* W1e = W1 + (size_t)e * NHID * NDIM;
    for (int idx = j; idx < 2048; idx += 256) {
        const int f = idx >> 5, c4 = idx & 31;
        float4 v = *(const float4*)(W1e + (size_t)(f0 + f) * NDIM + c4 * 4);
        short4 s; s.x = (short)f2bf(v.x); s.y = (short)f2bf(v.y);
        s.z = (short)f2bf(v.z); s.w = (short)f2bf(v.w);
        *(short4*)(Bsc + f * 272 + c4 * 8) = s;
    }
    const float bbias = B1[e * NHID + f0 + w * 16 + (lane & 15)];
    for (int bt = 0; bt * 32 < n; ++bt) {
        __syncthreads();
        if (j < 32) prs[j] = (bt * 32 + j < n) ? lst[bt * 32 + j] : -1;
        __syncthreads();
        for (int idx = j; idx < 1024; idx += 256) {
            const int tok = idx >> 5, c4 = idx & 31;
            const int pr = prs[tok];
            float4 v = make_float4(0.f, 0.f, 0.f, 0.f);
            if (pr >= 0) v = ((const float4*)x)[(size_t)(pr >> 1) * 32 + c4];
            short4 s; s.x = (short)f2bf(v.x); s.y = (short)f2bf(v.y);
            s.z = (short)f2bf(v.z); s.w = (short)f2bf(v.w);
            *(short4*)(Asc + tok * 272 + c4 * 8) = s;
        }
        __syncthreads();
        f32x4 acc[2];
        acc[0] = (f32x4){0.f, 0.f, 0.f, 0.f};
        acc[1] = (f32x4){0.f, 0.f, 0.f, 0.f};
        const int acol = ((lane >> 4) << 4);
        const int brow = w * 16 + (lane & 15);
#pragma unroll
        for (int ks = 0; ks < 4; ++ks) {
            short8_t b = *(short8_t*)(Bsc + brow * 272 + ks * 64 + acol);
#pragma unroll
            for (int mt = 0; mt < 2; ++mt) {
                short8_t a = *(short8_t*)(Asc + (mt * 16 + (lane & 15)) * 272 + ks * 64 + acol);
                acc[mt] = __builtin_amdgcn_mfma_f32_16x16x32_bf16(a, b, acc[mt], 0, 0, 0);
            }
        }
        const int fcol = f0 + w * 16 + (lane & 15);
#pragma unroll
        for (int mt = 0; mt < 2; ++mt) {
#pragma unroll
            for (int r = 0; r < 4; ++r) {
                const int tok = mt * 16 + ((lane >> 4) << 2) + r;
                const int pr = prs[tok];
                if (pr >= 0)
                    tbuf[(size_t)pr * NHID + fcol] = f2bf(gelu_f(acc[mt][r] + bbias));
            }
        }
    }
}

// ============ N5: expert layer2 (bf16 MFMA, split-K=4, XCD-local e) ============
__global__ __launch_bounds__(256) void k_l2(
        const float* __restrict__ W2, const int* __restrict__ eidx,
        const unsigned short* __restrict__ tbuf, float* __restrict__ pbuf) {
    __shared__ short As_[32 * 136];
    __shared__ short Bs_[64 * 136];
    __shared__ int prs[32];
    __shared__ int wtot[4];
    __shared__ int lst[NPAIR];
    const int j = threadIdx.x;
    const int lane = j & 63;
    const int w = j >> 6;
    const int e = blockIdx.x & 63;
    const int u = blockIdx.x >> 6;
    const int d0 = (u & 1) * 64;
    const int kz = u >> 1;
    const int k0 = kz * 128;
    char* Asc = (char*)As_;
    char* Bsc = (char*)Bs_;
    const int n = build_list(eidx, e, lane, w, lst, wtot);
    const float* W2e = W2 + (size_t)e * NDIM * NHID;
    for (int idx = j; idx < 2048; idx += 256) {
        const int d = idx >> 5, c4 = idx & 31;
        float4 v = *(const float4*)(W2e + (size_t)(d0 + d) * NHID + k0 + c4 * 4);
        short4 s; s.x = (short)f2bf(v.x); s.y = (short)f2bf(v.y);
        s.z = (short)f2bf(v.z); s.w = (short)f2bf(v.w);
        *(short4*)(Bsc + d * 272 + c4 * 8) = s;
    }
    float* pz = pbuf + (size_t)kz * NPAIR * NDIM;
    for (int bt = 0; bt * 32 < n; ++bt) {
        __syncthreads();
        if (j < 32) prs[j] = (bt * 32 + j < n) ? lst[bt * 32 + j] : -1;
        __syncthreads();
        for (int idx = j; idx < 512; idx += 256) {
            const int tok = idx >> 4, c8 = idx & 15;
            const int pr = prs[tok];
            short8_t v = (short8_t)(short)0;
            if (pr >= 0) v = *(const short8_t*)(tbuf + (size_t)pr * NHID + k0 + c8 * 8);
            *(short8_t*)(Asc + tok * 272 + c8 * 16) = v;
        }
        __syncthreads();
        f32x4 acc[2];
        acc[0] = (f32x4){0.f, 0.f, 0.f, 0.f};
        acc[1] = (f32x4){0.f, 0.f, 0.f, 0.f};
        const int acol = ((lane >> 4) << 4);
        const int brow = w * 16 + (lane & 15);
#pragma unroll
        for (int ks = 0; ks < 4; ++ks) {
            short8_t b = *(short8_t*)(Bsc + brow * 272 + ks * 64 + acol);
#pragma unroll
            for (int mt = 0; mt < 2; ++mt) {
                short8_t a = *(short8_t*)(Asc + (mt * 16 + (lane & 15)) * 272 + ks * 64 + acol);
                acc[mt] = __builtin_amdgcn_mfma_f32_16x16x32_bf16(a, b, acc[mt], 0, 0, 0);
            }
        }
        const int dcol = d0 + w * 16 + (lane & 15);
#pragma unroll
        for (int mt = 0; mt < 2; ++mt) {
#pragma unroll
            for (int r = 0; r < 4; ++r) {
                const int tok = mt * 16 + ((lane >> 4) << 2) + r;
                const int pr = prs[tok];
                if (pr >= 0) pz[(size_t)pr * NDIM + dcol] = acc[mt][r];
            }
        }
    }
}

// ============ N6: combine ============
__global__ __launch_bounds__(256) void k_combine(
        const float* __restrict__ pbuf, const float* __restrict__ wval,
        const int* __restrict__ eidx, const float* __restrict__ B2,
        float* __restrict__ out) {
    const int i = blockIdx.x * 256 + threadIdx.x;
    const int t = i >> 7, d = i & (NDIM - 1);
    const int KS = NPAIR * NDIM;
    float y[2];
#pragma unroll
    for (int k = 0; k < 2; ++k) {
        const int p = t * 2 + k;
        float s = pbuf[p * NDIM + d] + pbuf[KS + p * NDIM + d]
                + pbuf[2 * KS + p * NDIM + d] + pbuf[3 * KS + p * NDIM + d]
                + B2[eidx[p] * NDIM + d];
        y[k] = gelu_f(s);
    }
    out[i] = wval[t * 2] * y[0] + wval[t * 2 + 1] * y[1];
}

extern "C" void kernel_launch(void* const* d_in, const int* in_sizes, int n_in,
                              void* d_out, int out_size, void* d_ws, size_t ws_size,
                              hipStream_t stream) {
    const float* x   = (const float*)d_in[0];
    const float* gw1 = (const float*)d_in[1];
    const float* gb1 = (const float*)d_in[2];
    const float* gw2 = (const float*)d_in[3];
    const float* gb2 = (const float*)d_in[4];
    const float* gw3 = (const float*)d_in[5];
    const float* gb3 = (const float*)d_in[6];
    const float* W1  = (const float*)d_in[7];
    const float* B1  = (const float*)d_in[8];
    const float* W2  = (const float*)d_in[9];
    const float* B2  = (const float*)d_in[10];
    float* out = (float*)d_out;
    char* ws = (char*)d_ws;

    // G2 planes [0,1.5M) | H planes [1.5M,4.5M) | h2 [4.5M,6.5M) |
    // tbuf [0,2M) (aliases G2+Hh-head, dead after gate2) |
    // pbuf [2M,6M) (aliases Hm/Hl/h2-head, dead after gate2/gate3) | ctrl [7M..)
    unsigned short* G2h = (unsigned short*)(ws);
    unsigned short* G2m = (unsigned short*)(ws + 524288);
    unsigned short* G2l = (unsigned short*)(ws + 1048576);
    unsigned short* Hh  = (unsigned short*)(ws + 1572864);
    unsigned short* Hm  = (unsigned short*)(ws + 2621440);
    unsigned short* Hl  = (unsigned short*)(ws + 3670016);
    float*          h2  = (float*)(ws + 4718592);
    unsigned short* tbuf = (unsigned short*)(ws);
    float*          pbuf = (float*)(ws + 2097152);
    int*   eidx = (int*)  (ws + 7340032);
    float* wval = (float*)(ws + 7340032 + 8192);

    k_g1d2<<<dim3(320), 256, 0, stream>>>(x, gw1, gw2, gb1, G2h, G2m, G2l, Hh, Hm, Hl);
    k_gate2<<<dim3(256), 256, 0, stream>>>(Hh, Hm, Hl, G2h, G2m, G2l, gb2, h2);
    k_gate3<<<dim3(256), 256, 0, stream>>>(h2, gw3, gb3, eidx, wval);
    k_l1<<<dim3(512), 256, 0, stream>>>(x, W1, B1, eidx, tbuf);
    k_l2<<<dim3(512), 256, 0, stream>>>(W2, eidx, tbuf, pbuf);
    k_combine<<<dim3(512), 256, 0, stream>>>(pbuf, wval, eidx, B2, out);
}